// Round 2
// baseline (2172.934 us; speedup 1.0000x reference)
//
#include <hip/hip_runtime.h>
#include <hip/hip_bf16.h>
#include <hip/hip_fp16.h>
#include <stdint.h>

// y = (x @ W^T) * alpha + bias
// x: [M=8192, K=4096] fp32   W: [N=16384, K=4096] int8 -> delivered as int32!
// bias: [N] fp16   out: [M,N] fp32
// Strategy: pre-convert both operands to bf16 in d_ws (Wbf 128MiB + Xbf 64MiB,
// both L3-resident during GEMM), then m97-style 128x128 bf16 MFMA GEMM
// (16x16x32), global_load_lds width-16 staging, fused alpha+bias epilogue.

#define BM 128
#define BN 128
#define BK 32

typedef __attribute__((ext_vector_type(8))) short short8;   // 8 bf16 = 4 VGPRs
typedef __attribute__((ext_vector_type(4))) float floatx4;  // MFMA acc

__device__ inline void gld_lds16(const void* g, void* lds) {
  // async global->LDS, 16B/lane; LDS dest is wave-uniform base + lane*16
  __builtin_amdgcn_global_load_lds(
      (const __attribute__((address_space(1))) void*)g,
      (__attribute__((address_space(3))) void*)lds, 16, 0, 0);
}

__device__ inline unsigned short f2bf_rne(float f) {
  union { float f; unsigned int u; } v; v.f = f;
  unsigned int u = v.u;
  u += 0x7FFFu + ((u >> 16) & 1u);  // round-to-nearest-even
  return (unsigned short)(u >> 16);
}

// ---- convert x fp32 -> bf16, 8 elems/thread (memory-bound) ----
__global__ __launch_bounds__(256) void cvt_x(const float* __restrict__ x,
                                             unsigned short* __restrict__ o) {
  long t = (long)blockIdx.x * 256 + threadIdx.x;
  long base = t * 8;
  const float4* xv = (const float4*)(x + base);
  float4 a = xv[0], b = xv[1];
  union { unsigned short s[8]; uint4 v; } r;
  r.s[0] = f2bf_rne(a.x); r.s[1] = f2bf_rne(a.y);
  r.s[2] = f2bf_rne(a.z); r.s[3] = f2bf_rne(a.w);
  r.s[4] = f2bf_rne(b.x); r.s[5] = f2bf_rne(b.y);
  r.s[6] = f2bf_rne(b.z); r.s[7] = f2bf_rne(b.w);
  *((uint4*)(o + base)) = r.v;
}

// ---- convert W int32 (one int8 value per int32!) -> bf16, 8 elems/thread ----
__global__ __launch_bounds__(256) void cvt_w(const int* __restrict__ w,
                                             unsigned short* __restrict__ o) {
  long t = (long)blockIdx.x * 256 + threadIdx.x;
  long base = t * 8;
  const int4 a = ((const int4*)(w + base))[0];
  const int4 b = ((const int4*)(w + base))[1];
  union { unsigned short s[8]; uint4 v; } r;
  r.s[0] = f2bf_rne((float)a.x);  // |v|<=127: exact in bf16
  r.s[1] = f2bf_rne((float)a.y);
  r.s[2] = f2bf_rne((float)a.z);
  r.s[3] = f2bf_rne((float)a.w);
  r.s[4] = f2bf_rne((float)b.x);
  r.s[5] = f2bf_rne((float)b.y);
  r.s[6] = f2bf_rne((float)b.z);
  r.s[7] = f2bf_rne((float)b.w);
  *((uint4*)(o + base)) = r.v;
}

// ---- main GEMM: C[m][n] = sum_k A[m][k]*Bt[n][k], both bf16 K-major ----
__global__ __launch_bounds__(256) void gemm_bt(
    const unsigned short* __restrict__ A,   // [M][K] bf16
    const unsigned short* __restrict__ Bt,  // [N][K] bf16
    const __half* __restrict__ bias,        // [N] fp16
    const float* __restrict__ alpha_p,
    float* __restrict__ C, int M, int N, int K) {
  __shared__ unsigned short As[BM * BK];  // 8 KiB, row-major, row stride 32
  __shared__ unsigned short Bs[BN * BK];  // 8 KiB

  const int tid  = threadIdx.x;
  const int wave = tid >> 6;
  const int lane = tid & 63;
  const int bm = blockIdx.y, bn = blockIdx.x;

  const int wm = (wave >> 1) * 64;  // wave's 64x64 quadrant
  const int wn = (wave & 1) * 64;

  floatx4 acc[4][4];
#pragma unroll
  for (int i = 0; i < 4; i++)
#pragma unroll
    for (int j = 0; j < 4; j++) acc[i][j] = (floatx4){0.f, 0.f, 0.f, 0.f};

  // staging: 16 chunks of 1KiB (16 rows each); wave w stages chunks {w, w+4}
  // of both A and B. lane -> row = chunk*16 + lane/4, k = (lane%4)*8.
  // LDS ushort offset = lane*8 = (lane>>2)*32 + (lane&3)*8 -> As[row*32 + k].
  const int rA = lane >> 2;
  const int kA = (lane & 3) * 8;
  const long a_row0 = (long)bm * BM;
  const long b_row0 = (long)bn * BN;
  const int c0 = wave, c1 = wave + 4;

  const unsigned short* Ag0 = A  + (a_row0 + c0 * 16 + rA) * (long)K + kA;
  const unsigned short* Ag1 = A  + (a_row0 + c1 * 16 + rA) * (long)K + kA;
  const unsigned short* Bg0 = Bt + (b_row0 + c0 * 16 + rA) * (long)K + kA;
  const unsigned short* Bg1 = Bt + (b_row0 + c1 * 16 + rA) * (long)K + kA;
  unsigned short* AsC0 = As + c0 * 512;  // 1 KiB = 512 ushorts, wave-uniform
  unsigned short* AsC1 = As + c1 * 512;
  unsigned short* BsC0 = Bs + c0 * 512;
  unsigned short* BsC1 = Bs + c1 * 512;

  // fragment addressing: A-frag lane -> row = lane&15, k = (lane>>4)*8
  const int fr = lane & 15;
  const int fk = (lane >> 4) * 8;

  for (int k0 = 0; k0 < K; k0 += BK) {
    gld_lds16(Ag0 + k0, AsC0);
    gld_lds16(Ag1 + k0, AsC1);
    gld_lds16(Bg0 + k0, BsC0);
    gld_lds16(Bg1 + k0, BsC1);
    __syncthreads();  // compiler emits vmcnt(0) drain here

    short8 af[4], bf[4];
#pragma unroll
    for (int i = 0; i < 4; i++)
      af[i] = *(const short8*)(As + (wm + i * 16 + fr) * BK + fk);
#pragma unroll
    for (int j = 0; j < 4; j++)
      bf[j] = *(const short8*)(Bs + (wn + j * 16 + fr) * BK + fk);
#pragma unroll
    for (int i = 0; i < 4; i++)
#pragma unroll
      for (int j = 0; j < 4; j++)
        acc[i][j] = __builtin_amdgcn_mfma_f32_16x16x32_bf16(af[i], bf[j],
                                                            acc[i][j], 0, 0, 0);
    __syncthreads();  // protect LDS from next iteration's staging
  }

  // epilogue: C/D layout col=lane&15, row=(lane>>4)*4+r  [m89/m91-verified]
  const float alpha = *alpha_p;
  const int erow = (lane >> 4) * 4;
  const int ecol = lane & 15;
#pragma unroll
  for (int j = 0; j < 4; j++) {
    const int col = (int)(b_row0 + wn + j * 16 + ecol);
    const float bv = __half2float(bias[col]);
#pragma unroll
    for (int i = 0; i < 4; i++) {
      const long row = a_row0 + wm + i * 16 + erow;
#pragma unroll
      for (int r = 0; r < 4; r++)
        C[(row + r) * (long)N + col] = acc[i][j][r] * alpha + bv;
    }
  }
}

extern "C" void kernel_launch(void* const* d_in, const int* in_sizes, int n_in,
                              void* d_out, int out_size, void* d_ws, size_t ws_size,
                              hipStream_t stream) {
  const float* x        = (const float*)d_in[0];  // [M,K] fp32
  const int*   w        = (const int*)d_in[1];    // [N,K] int32 (widened int8)
  const __half* bias    = (const __half*)d_in[2]; // [N] fp16 (all zeros)
  const float* alpha    = (const float*)d_in[3];  // scalar fp32
  float* out            = (float*)d_out;

  const int K = 4096;
  const int N = in_sizes[2];            // 16384
  const int M = in_sizes[0] / K;        // 8192

  // workspace: [ W bf16 : N*K*2 B = 128 MiB ][ X bf16 : M*K*2 B = 64 MiB ]
  unsigned short* Wbf = (unsigned short*)d_ws;
  unsigned short* Xbf = Wbf + (size_t)N * K;
  (void)ws_size; (void)n_in; (void)out_size;

  {  // W: N*K/8 threads, 8 int32 -> 8 bf16 each
    long nthreads = (long)N * K / 8;
    cvt_w<<<dim3((unsigned)(nthreads / 256)), dim3(256), 0, stream>>>(w, Wbf);
  }
  {  // X: M*K/8 threads
    long nthreads = (long)M * K / 8;
    cvt_x<<<dim3((unsigned)(nthreads / 256)), dim3(256), 0, stream>>>(x, Xbf);
  }
  gemm_bt<<<dim3(N / BN, M / BM), dim3(256), 0, stream>>>(Xbf, Wbf, bias, alpha,
                                                          out, M, N, K);
}